// Round 11
// baseline (9102.442 us; speedup 1.0000x reference)
//
#include <hip/hip_runtime.h>
#include <hip/hip_bf16.h>

// Problem constants (fixed by the reference)
#define L     4096
#define E     512
#define HID   1024
#define HH    512          // H per direction
#define G4    2048         // 4*H gate rows
#define T_TAG 7
#define START_TAG 4
#define STOP_TAG  5
#define NEGV  (-10000.0f)

#define NWRK  32           // worker blocks (16 per direction)
#define NHELP 224          // helper blocks (xg tiles, then feats rows)
#define NTILE (64 * 2 * 32)  // (L/64 s-chunks) x 2 dirs x (G4/64 j-tiles)
#define SENT  0xFFFFFFFFu  // h sentinel: -NaN, unreachable for real h values

__device__ __forceinline__ float aload_f(const float* p) {
    const unsigned int v = __hip_atomic_load((const unsigned int*)p,
                                             __ATOMIC_RELAXED,
                                             __HIP_MEMORY_SCOPE_AGENT);
    return __uint_as_float(v);
}
__device__ __forceinline__ void astore_f(float* p, float x) {
    __hip_atomic_store((unsigned int*)p, __float_as_uint(x),
                       __ATOMIC_RELAXED, __HIP_MEMORY_SCOPE_AGENT);
}

// ---------------------------------------------------------------------------
// Fused cooperative kernel, 256 blocks x 512.  (unchanged — measured at the
// recurrence floor 7.8ms with helpers fully hidden)
// ---------------------------------------------------------------------------
__global__ __launch_bounds__(512)
void fused_kernel(const int* __restrict__ sentence, const float* __restrict__ emb,
                  const float* __restrict__ wih_f, const float* __restrict__ bih_f,
                  const float* __restrict__ bhh_f,
                  const float* __restrict__ wih_b, const float* __restrict__ bih_b,
                  const float* __restrict__ bhh_b,
                  const float* __restrict__ whh_f, const float* __restrict__ whh_b,
                  const float* __restrict__ wout, const float* __restrict__ bout,
                  float* __restrict__ xg_f, float* __restrict__ xg_b,
                  float* __restrict__ hf, float* __restrict__ hb,
                  float* __restrict__ feats, int* cnt)
{
    const int bid = blockIdx.x;
    const int tid = threadIdx.x;

    __shared__ float h_lds[2][HH];
    __shared__ float glds[8][16];
    __shared__ float As[32][68];
    __shared__ float Bs[32][68];
    __shared__ int   sent_s[64];
    __shared__ float red_s[8][8];

    if (bid < NWRK) {
        const int dir = bid >> 4;
        const int rnk = bid & 15;

        const float* __restrict__ xg  = dir ? xg_b  : xg_f;
        const float* __restrict__ whh = dir ? whh_b : whh_f;
        float* __restrict__ hout = dir ? hb : hf;

        const int wave = tid >> 6;
        const int lane = tid & 63;
        const int g    = wave >> 1;
        const int jh   = wave & 1;
        const int u0   = rnk * 32;

        float w[16][8];
#pragma unroll
        for (int rr = 0; rr < 16; rr++) {
            const size_t row = (size_t)(g * HH + u0 + jh * 16 + rr);
#pragma unroll
            for (int k = 0; k < 8; k++)
                w[rr][k] = whh[row * HH + (size_t)(k * 64 + lane)];
        }

        float c_state = 0.f;
        const int uu = u0 + (tid & 31);

        auto wait_chunk = [&](int tc) {
            const int* cp = cnt + dir * 64 + tc;
            while (__hip_atomic_load(cp, __ATOMIC_ACQUIRE,
                                     __HIP_MEMORY_SCOPE_AGENT) < 32) {
                __builtin_amdgcn_s_sleep(1);
            }
        };

        float xq0 = 0.f, xq1 = 0.f, xq2 = 0.f, xq3 = 0.f;
        if (tid < 32) {
            wait_chunk(dir ? 63 : 0);
            const float* xgt = xg + (size_t)(dir ? (L - 1) : 0) * G4;
            xq0 = aload_f(xgt + uu);            xq1 = aload_f(xgt + HH + uu);
            xq2 = aload_f(xgt + 2 * HH + uu);   xq3 = aload_f(xgt + 3 * HH + uu);
        }

        for (int s = 0; s < L; s++) {
            const int t = dir ? (L - 1 - s) : s;
            const int p = s & 1;

            unsigned int v = 0;
            if (s > 0) {
                const int tp = dir ? (t + 1) : (t - 1);
                const unsigned int* hp =
                    (const unsigned int*)(hout + (size_t)tp * HH) + tid;
                do {
                    v = __hip_atomic_load(hp, __ATOMIC_RELAXED,
                                          __HIP_MEMORY_SCOPE_AGENT);
                } while (v == SENT);
            }
            h_lds[p][tid] = __uint_as_float(v);
            __syncthreads();                               // barrier 1

            float hv[8];
#pragma unroll
            for (int k = 0; k < 8; k++) hv[k] = h_lds[p][k * 64 + lane];

            float acc[16];
#pragma unroll
            for (int rr = 0; rr < 16; rr++) {
                float a = 0.f;
#pragma unroll
                for (int k = 0; k < 8; k++) a += w[rr][k] * hv[k];
                acc[rr] = a;
            }

            {
                const bool b0 = lane & 1;
#pragma unroll
                for (int r = 0; r < 8; r++) {
                    const float send = b0 ? acc[r] : acc[r + 8];
                    const float recv = __shfl_xor(send, 1, 64);
                    acc[r] = (b0 ? acc[r + 8] : acc[r]) + recv;
                }
                const bool b1 = lane & 2;
#pragma unroll
                for (int r = 0; r < 4; r++) {
                    const float send = b1 ? acc[r] : acc[r + 4];
                    const float recv = __shfl_xor(send, 2, 64);
                    acc[r] = (b1 ? acc[r + 4] : acc[r]) + recv;
                }
                const bool b2 = lane & 4;
#pragma unroll
                for (int r = 0; r < 2; r++) {
                    const float send = b2 ? acc[r] : acc[r + 2];
                    const float recv = __shfl_xor(send, 4, 64);
                    acc[r] = (b2 ? acc[r + 2] : acc[r]) + recv;
                }
                const bool b3 = lane & 8;
                {
                    const float send = b3 ? acc[0] : acc[1];
                    const float recv = __shfl_xor(send, 8, 64);
                    acc[0] = (b3 ? acc[1] : acc[0]) + recv;
                }
                acc[0] += __shfl_xor(acc[0], 16, 64);
                acc[0] += __shfl_xor(acc[0], 32, 64);
            }
            if (lane < 16) {
                const int R = ((lane & 1) << 3) | ((lane & 2) << 1) |
                              ((lane & 4) >> 1) | ((lane & 8) >> 3);
                glds[wave][R] = acc[0];
            }
            __syncthreads();                               // barrier 2

            if (tid < 32) {
                const int jh_ = tid >> 4;
                const int rr  = tid & 15;
                float iv = glds[0 + jh_][rr] + xq0;
                float fv = glds[2 + jh_][rr] + xq1;
                float gv = glds[4 + jh_][rr] + xq2;
                float ov = glds[6 + jh_][rr] + xq3;
                iv = 1.f / (1.f + expf(-iv));
                fv = 1.f / (1.f + expf(-fv));
                gv = tanhf(gv);
                ov = 1.f / (1.f + expf(-ov));
                c_state = fv * c_state + iv * gv;
                const float hval = ov * tanhf(c_state);
                __hip_atomic_store((unsigned int*)&hout[(size_t)t * HH + uu],
                                   __float_as_uint(hval), __ATOMIC_RELAXED,
                                   __HIP_MEMORY_SCOPE_AGENT);
                if (s + 1 < L) {
                    const int tn = dir ? (t - 1) : (t + 1);
                    if ((tn & 63) == (dir ? 63 : 0)) wait_chunk(tn >> 6);
                    const float* xgt = xg + (size_t)tn * G4;
                    xq0 = aload_f(xgt + uu);
                    xq1 = aload_f(xgt + HH + uu);
                    xq2 = aload_f(xgt + 2 * HH + uu);
                    xq3 = aload_f(xgt + 3 * HH + uu);
                }
            }
        }
        return;
    }

    // ====================== HELPER blocks ======================
    const int hid_ = bid - NWRK;

    for (int tile = hid_; tile < NTILE; tile += NHELP) {
        const int jt = tile & 31;
        const int sd = tile >> 5;
        const int dr = sd & 1;
        const int sc = sd >> 1;
        const int t0 = dr ? (L - 64 - sc * 64) : (sc * 64);
        const int j0 = jt * 64;
        const float* __restrict__ wih = dr ? wih_b : wih_f;
        const float* __restrict__ bih = dr ? bih_b : bih_f;
        const float* __restrict__ bhh = dr ? bhh_b : bhh_f;
        float* __restrict__ xg = dr ? xg_b : xg_f;

        if (tid < 64) sent_s[tid] = sentence[t0 + tid];

        const int li = tid >> 3;
        const int k4 = (tid & 7) * 4;
        const int tx = tid & 15;
        const int ty = tid >> 4;

        float a00 = 0.f, a01 = 0.f, a02 = 0.f, a03 = 0.f;
        float a10 = 0.f, a11 = 0.f, a12 = 0.f, a13 = 0.f;

        for (int k0 = 0; k0 < E; k0 += 32) {
            __syncthreads();
            {
                const float4 av = *(const float4*)(emb + (size_t)sent_s[li] * E + k0 + k4);
                As[k4 + 0][li] = av.x; As[k4 + 1][li] = av.y;
                As[k4 + 2][li] = av.z; As[k4 + 3][li] = av.w;
                const float4 bv = *(const float4*)(wih + (size_t)(j0 + li) * E + k0 + k4);
                Bs[k4 + 0][li] = bv.x; Bs[k4 + 1][li] = bv.y;
                Bs[k4 + 2][li] = bv.z; Bs[k4 + 3][li] = bv.w;
            }
            __syncthreads();
#pragma unroll
            for (int k = 0; k < 32; k++) {
                const float a0 = As[k][ty * 2 + 0];
                const float a1 = As[k][ty * 2 + 1];
                const float4 b4 = *(const float4*)&Bs[k][tx * 4];
                a00 += a0 * b4.x; a01 += a0 * b4.y; a02 += a0 * b4.z; a03 += a0 * b4.w;
                a10 += a1 * b4.x; a11 += a1 * b4.y; a12 += a1 * b4.z; a13 += a1 * b4.w;
            }
        }

        {
            const int c0 = j0 + tx * 4;
            const float bsum0 = bih[c0 + 0] + bhh[c0 + 0];
            const float bsum1 = bih[c0 + 1] + bhh[c0 + 1];
            const float bsum2 = bih[c0 + 2] + bhh[c0 + 2];
            const float bsum3 = bih[c0 + 3] + bhh[c0 + 3];
            float* r0 = xg + (size_t)(t0 + ty * 2 + 0) * G4 + c0;
            float* r1 = xg + (size_t)(t0 + ty * 2 + 1) * G4 + c0;
            astore_f(r0 + 0, a00 + bsum0); astore_f(r0 + 1, a01 + bsum1);
            astore_f(r0 + 2, a02 + bsum2); astore_f(r0 + 3, a03 + bsum3);
            astore_f(r1 + 0, a10 + bsum0); astore_f(r1 + 1, a11 + bsum1);
            astore_f(r1 + 2, a12 + bsum2); astore_f(r1 + 3, a13 + bsum3);
        }
        __syncthreads();
        if (tid == 0)
            __hip_atomic_fetch_add(&cnt[dr * 64 + (t0 >> 6)], 1,
                                   __ATOMIC_RELEASE, __HIP_MEMORY_SCOPE_AGENT);
    }

    const int wave = tid >> 6, lane = tid & 63;
    for (int t = hid_; t < L; t += NHELP) {
        if (tid < 32) {
            const float* src = (tid < 16) ? hf : hb;
            const unsigned int* wp =
                (const unsigned int*)(src + (size_t)t * HH) + (tid & 15) * 32;
            while (__hip_atomic_load(wp, __ATOMIC_RELAXED,
                                     __HIP_MEMORY_SCOPE_AGENT) == SENT) {
                __builtin_amdgcn_s_sleep(8);
            }
        }
        __syncthreads();

        const unsigned int* p0 = (const unsigned int*)(hf + (size_t)t * HH) + tid;
        const unsigned int* p1 = (const unsigned int*)(hb + (size_t)t * HH) + tid;
        unsigned int v0, v1;
        do { v0 = __hip_atomic_load(p0, __ATOMIC_RELAXED,
                                    __HIP_MEMORY_SCOPE_AGENT); } while (v0 == SENT);
        do { v1 = __hip_atomic_load(p1, __ATOMIC_RELAXED,
                                    __HIP_MEMORY_SCOPE_AGENT); } while (v1 == SENT);
        const float x0 = __uint_as_float(v0);
        const float x1 = __uint_as_float(v1);

        float acc[T_TAG];
#pragma unroll
        for (int i = 0; i < T_TAG; i++)
            acc[i] = x0 * wout[i * HID + tid] + x1 * wout[i * HID + HH + tid];
#pragma unroll
        for (int m = 1; m < 64; m <<= 1) {
#pragma unroll
            for (int i = 0; i < T_TAG; i++) acc[i] += __shfl_xor(acc[i], m, 64);
        }
        if (lane == 0) {
#pragma unroll
            for (int i = 0; i < T_TAG; i++) red_s[wave][i] = acc[i];
        }
        __syncthreads();
        if (tid < T_TAG) {
            float ssum = bout[tid];
#pragma unroll
            for (int wv = 0; wv < 8; wv++) ssum += red_s[wv][tid];
            feats[(size_t)t * 8 + tid] = ssum;
        }
        __syncthreads();
    }
}

// ---------------------------------------------------------------------------
// Viterbi: zero-cross-lane forward scan + parallel backtrace.  One wave.
// Every lane replicates the full 7-wide fv update in pure VALU (49 adds +
// max3 trees) -> no DS/shfl on the per-step dependency chain.  Lane d<7
// additionally tracks argmax for dest d (own trans row in VGPRs) and stores
// bp.  Backtrace: per-lane 64-step bp-map composition, lane-0 block walk,
// per-lane path regeneration (~12us vs 200us serial).
// ---------------------------------------------------------------------------
__global__ __launch_bounds__(64)
void viterbi_kernel(const float* __restrict__ feats, const float* __restrict__ trans,
                    float* __restrict__ out)
{
    __shared__ unsigned char bp[L][8];      // 32 KiB, [t][dest]
    __shared__ unsigned char gl[64][8];     // per-block composed maps
    __shared__ unsigned char bnd[64];       // block entry tags

    const int tid = threadIdx.x;            // 0..63

    // full transition matrix, replicated (uniform loads -> SGPR-friendly)
    float tr[T_TAG][T_TAG];
#pragma unroll
    for (int i = 0; i < T_TAG; i++)
#pragma unroll
        for (int j = 0; j < T_TAG; j++) tr[i][j] = trans[i * T_TAG + j];

    // this lane's argmax row (dest d = tid % 7); runtime address, static regs
    const int d = tid % T_TAG;
    float trd[T_TAG];
#pragma unroll
    for (int j = 0; j < T_TAG; j++) trd[j] = trans[d * T_TAG + j];

    // terminal row
    float trS[T_TAG];
#pragma unroll
    for (int j = 0; j < T_TAG; j++) trS[j] = trans[STOP_TAG * T_TAG + j];

    float fv0 = NEGV, fv1 = NEGV, fv2 = NEGV, fv3 = NEGV,
          fv4 = 0.f,  fv5 = NEGV, fv6 = NEGV;       // START_TAG = 4

    // feats queue: 8 steps x (float4 lo + float4 hi), static-indexed
    float4 qa[8], qb[8];
#pragma unroll
    for (int q = 0; q < 8; q++) {
        qa[q] = *(const float4*)(feats + (size_t)q * 8);
        qb[q] = *(const float4*)(feats + (size_t)q * 8 + 4);
    }

#define VMAXROW(I, OUT, FI)                                                    \
    {                                                                          \
        const float a0 = fv0 + tr[I][0], a1 = fv1 + tr[I][1];                  \
        const float a2 = fv2 + tr[I][2], a3 = fv3 + tr[I][3];                  \
        const float a4 = fv4 + tr[I][4], a5 = fv5 + tr[I][5];                  \
        const float a6 = fv6 + tr[I][6];                                       \
        const float m012 = fmaxf(fmaxf(a0, a1), a2);                           \
        const float m345 = fmaxf(fmaxf(a3, a4), a5);                           \
        OUT = fmaxf(fmaxf(m012, m345), a6) + (FI);                             \
    }

#define VSTEP(T, Q, PRE)                                                       \
    {                                                                          \
        const float4 fa = qa[Q], fb = qb[Q];                                   \
        /* per-lane argmax (first-index tie-break via strict >) */             \
        {                                                                      \
            float bv_ = fv0 + trd[0]; int bj_ = 0; float c_;                   \
            c_ = fv1 + trd[1]; if (c_ > bv_) { bv_ = c_; bj_ = 1; }            \
            c_ = fv2 + trd[2]; if (c_ > bv_) { bv_ = c_; bj_ = 2; }            \
            c_ = fv3 + trd[3]; if (c_ > bv_) { bv_ = c_; bj_ = 3; }            \
            c_ = fv4 + trd[4]; if (c_ > bv_) { bv_ = c_; bj_ = 4; }            \
            c_ = fv5 + trd[5]; if (c_ > bv_) { bv_ = c_; bj_ = 5; }            \
            c_ = fv6 + trd[6]; if (c_ > bv_) { bv_ = c_; bj_ = 6; }            \
            if (tid < T_TAG) bp[(T)][tid] = (unsigned char)bj_;                \
        }                                                                      \
        /* replicated fv update (pure VALU, bit-exact vs reference) */         \
        float nf0, nf1, nf2, nf3, nf4, nf5, nf6;                               \
        VMAXROW(0, nf0, fa.x) VMAXROW(1, nf1, fa.y) VMAXROW(2, nf2, fa.z)      \
        VMAXROW(3, nf3, fa.w) VMAXROW(4, nf4, fb.x) VMAXROW(5, nf5, fb.y)      \
        VMAXROW(6, nf6, fb.z)                                                  \
        fv0 = nf0; fv1 = nf1; fv2 = nf2; fv3 = nf3;                            \
        fv4 = nf4; fv5 = nf5; fv6 = nf6;                                       \
        if (PRE) {                                                             \
            qa[Q] = *(const float4*)(feats + (size_t)((T) + 8) * 8);           \
            qb[Q] = *(const float4*)(feats + (size_t)((T) + 8) * 8 + 4);       \
        }                                                                      \
    }

    for (int tb = 0; tb < L - 8; tb += 8) {
#pragma unroll
        for (int q = 0; q < 8; q++) VSTEP(tb + q, q, true)
    }
    {
        const int tb = L - 8;
#pragma unroll
        for (int q = 0; q < 8; q++) VSTEP(tb + q, q, false)
    }
#undef VSTEP
#undef VMAXROW

    // terminal argmax (replicated, ascending strict > = first index)
    int bt_final; float best_score;
    {
        float bv_ = fv0 + trS[0]; int bj_ = 0; float c_;
        c_ = fv1 + trS[1]; if (c_ > bv_) { bv_ = c_; bj_ = 1; }
        c_ = fv2 + trS[2]; if (c_ > bv_) { bv_ = c_; bj_ = 2; }
        c_ = fv3 + trS[3]; if (c_ > bv_) { bv_ = c_; bj_ = 3; }
        c_ = fv4 + trS[4]; if (c_ > bv_) { bv_ = c_; bj_ = 4; }
        c_ = fv5 + trS[5]; if (c_ > bv_) { bv_ = c_; bj_ = 5; }
        c_ = fv6 + trS[6]; if (c_ > bv_) { bv_ = c_; bj_ = 6; }
        bt_final = bj_; best_score = bv_;
    }
    __syncthreads();   // bp writes visible to all lanes

    // Phase A: lane l composes bp maps for t in [64l+1 .. min(64l+64, L-1)]
    const int lo = 64 * tid + 1;
    const int hi = (tid == 63) ? (L - 1) : (64 * tid + 64);
    {
        unsigned int c0 = 0, c1 = 1, c2 = 2, c3 = 3, c4 = 4, c5 = 5, c6 = 6;
        for (int t = hi; t >= lo; --t) {
            const unsigned char* row = &bp[t][0];
            c0 = row[c0]; c1 = row[c1]; c2 = row[c2]; c3 = row[c3];
            c4 = row[c4]; c5 = row[c5]; c6 = row[c6];
        }
        gl[tid][0] = (unsigned char)c0; gl[tid][1] = (unsigned char)c1;
        gl[tid][2] = (unsigned char)c2; gl[tid][3] = (unsigned char)c3;
        gl[tid][4] = (unsigned char)c4; gl[tid][5] = (unsigned char)c5;
        gl[tid][6] = (unsigned char)c6;
    }
    __syncthreads();

    // Phase B: lane 0 walks block maps to get each block's entry tag
    if (tid == 0) {
        int b = bt_final;
        for (int l2 = 63; l2 >= 0; --l2) {
            bnd[l2] = (unsigned char)b;
            b = gl[l2][b];
        }
    }
    __syncthreads();

    // Phase C: each lane regenerates its block's path
    {
        int tag = bnd[tid];
        for (int t = hi; t >= lo; --t) {
            tag = bp[t][tag];
            out[t - 1] = (float)tag;
        }
    }
    if (tid == 63) {
        out[L - 1] = (float)bt_final;
        out[L]     = best_score;
    }
}

// ---------------------------------------------------------------------------
extern "C" void kernel_launch(void* const* d_in, const int* in_sizes, int n_in,
                              void* d_out, int out_size, void* d_ws, size_t ws_size,
                              hipStream_t stream)
{
    const int*   sentence = (const int*)  d_in[0];
    const float* emb      = (const float*)d_in[1];
    const float* wih_f    = (const float*)d_in[2];
    const float* whh_f    = (const float*)d_in[3];
    const float* bih_f    = (const float*)d_in[4];
    const float* bhh_f    = (const float*)d_in[5];
    const float* wih_b    = (const float*)d_in[6];
    const float* whh_b    = (const float*)d_in[7];
    const float* bih_b    = (const float*)d_in[8];
    const float* bhh_b    = (const float*)d_in[9];
    const float* wout     = (const float*)d_in[10];
    const float* bout     = (const float*)d_in[11];
    const float* trans    = (const float*)d_in[12];
    float* out = (float*)d_out;

    char* ws = (char*)d_ws;
    int*   cnt    = (int*)ws;                                   // 1 KiB
    float* xg_f   = (float*)(ws + 1024);
    float* xg_b   = xg_f  + (size_t)L * G4;
    float* hfbuf  = xg_b  + (size_t)L * G4;
    float* hbbuf  = hfbuf + (size_t)L * HH;
    float* featsb = hbbuf + (size_t)L * HH;
    // total: 1024 + 2*L*G4*4 + 2*L*HH*4 + L*8*4  ~= 84 MB

    hipMemsetAsync(cnt, 0, 1024, stream);
    hipMemsetAsync(hfbuf, 0xFF, (size_t)2 * L * HH * sizeof(float), stream);

    void* args[] = { (void*)&sentence, (void*)&emb,
                     (void*)&wih_f, (void*)&bih_f, (void*)&bhh_f,
                     (void*)&wih_b, (void*)&bih_b, (void*)&bhh_b,
                     (void*)&whh_f, (void*)&whh_b,
                     (void*)&wout, (void*)&bout,
                     (void*)&xg_f, (void*)&xg_b,
                     (void*)&hfbuf, (void*)&hbbuf,
                     (void*)&featsb, (void*)&cnt };
    hipLaunchCooperativeKernel((void*)fused_kernel, dim3(NWRK + NHELP),
                               dim3(512), args, 0, stream);

    hipLaunchKernelGGL(viterbi_kernel, dim3(1), dim3(64), 0, stream,
                       featsb, trans, out);
}

// Round 13
// 8724.344 us; speedup vs baseline: 1.0433x; 1.0433x over previous
//
#include <hip/hip_runtime.h>
#include <hip/hip_bf16.h>

// Problem constants (fixed by the reference)
#define L     4096
#define E     512
#define HID   1024
#define HH    512          // H per direction
#define G4    2048         // 4*H gate rows
#define T_TAG 7
#define START_TAG 4
#define STOP_TAG  5
#define NEGV  (-10000.0f)

#define NWRK  32           // worker blocks (16 per direction)
#define VITB  32           // viterbi block id
#define NHELP 223          // helper blocks (33..255)
#define NTILE (64 * 2 * 32)  // (L/64 s-chunks) x 2 dirs x (G4/64 j-tiles)
#define SENT  0xFFFFFFFFu  // sentinel: -NaN, unreachable for real values

__device__ __forceinline__ unsigned int aload_u(const float* p) {
    return __hip_atomic_load((const unsigned int*)p, __ATOMIC_RELAXED,
                             __HIP_MEMORY_SCOPE_AGENT);
}
__device__ __forceinline__ float aload_f(const float* p) {
    return __uint_as_float(aload_u(p));
}
__device__ __forceinline__ void astore_f(float* p, float x) {
    __hip_atomic_store((unsigned int*)p, __float_as_uint(x),
                       __ATOMIC_RELAXED, __HIP_MEMORY_SCOPE_AGENT);
}

// LDS role overlay
union SMem {
    struct { float h_lds[2][HH]; float glds[8][16]; } wk;                 // 4.6 KB
    struct { float As[32][68]; float Bs[32][68]; int sent[64];
             float red[8][8]; } hp;                                       // 17.9 KB
    struct { unsigned char bp[L][8]; float stage[2][32][8];
             unsigned char gl[64][8]; unsigned char bnd[64]; } vt;        // 34.6 KB
};

// ---------------------------------------------------------------------------
// Fused cooperative kernel, 256 blocks x 512.
//  blocks 0..31  : bidirectional LSTM recurrence (proven floor ~1.9us/step)
//  block  32     : Viterbi (1 wave): sentinel-polls feats (cols 0..6 only —
//                  col 7 is padding), batch-staged LDS pipeline,
//                  replicated-VALU scan, parallel backtrace -> out
//  blocks 33..255: helpers (xg tiles, then feats rows; agent-scope stores,
//                  ALL 8 columns written — col 7 = 0 to clear the poison)
// ---------------------------------------------------------------------------
__global__ __launch_bounds__(512)
void fused_kernel(const int* __restrict__ sentence, const float* __restrict__ emb,
                  const float* __restrict__ wih_f, const float* __restrict__ bih_f,
                  const float* __restrict__ bhh_f,
                  const float* __restrict__ wih_b, const float* __restrict__ bih_b,
                  const float* __restrict__ bhh_b,
                  const float* __restrict__ whh_f, const float* __restrict__ whh_b,
                  const float* __restrict__ wout, const float* __restrict__ bout,
                  const float* __restrict__ trans,
                  float* __restrict__ xg_f, float* __restrict__ xg_b,
                  float* __restrict__ hf, float* __restrict__ hb,
                  float* __restrict__ feats, float* __restrict__ out, int* cnt)
{
    const int bid = blockIdx.x;
    const int tid = threadIdx.x;

    __shared__ SMem sm;

    if (bid < NWRK) {
        // =================== WORKER: LSTM recurrence ===================
        const int dir = bid >> 4;
        const int rnk = bid & 15;

        const float* __restrict__ xg  = dir ? xg_b  : xg_f;
        const float* __restrict__ whh = dir ? whh_b : whh_f;
        float* __restrict__ hout = dir ? hb : hf;

        const int wave = tid >> 6;
        const int lane = tid & 63;
        const int g    = wave >> 1;
        const int jh   = wave & 1;
        const int u0   = rnk * 32;

        float w[16][8];
#pragma unroll
        for (int rr = 0; rr < 16; rr++) {
            const size_t row = (size_t)(g * HH + u0 + jh * 16 + rr);
#pragma unroll
            for (int k = 0; k < 8; k++)
                w[rr][k] = whh[row * HH + (size_t)(k * 64 + lane)];
        }

        float c_state = 0.f;
        const int uu = u0 + (tid & 31);

        auto wait_chunk = [&](int tc) {
            const int* cp = cnt + dir * 64 + tc;
            while (__hip_atomic_load(cp, __ATOMIC_ACQUIRE,
                                     __HIP_MEMORY_SCOPE_AGENT) < 32) {
                __builtin_amdgcn_s_sleep(1);
            }
        };

        float xq0 = 0.f, xq1 = 0.f, xq2 = 0.f, xq3 = 0.f;
        if (tid < 32) {
            wait_chunk(dir ? 63 : 0);
            const float* xgt = xg + (size_t)(dir ? (L - 1) : 0) * G4;
            xq0 = aload_f(xgt + uu);            xq1 = aload_f(xgt + HH + uu);
            xq2 = aload_f(xgt + 2 * HH + uu);   xq3 = aload_f(xgt + 3 * HH + uu);
        }

        for (int s = 0; s < L; s++) {
            const int t = dir ? (L - 1 - s) : s;
            const int p = s & 1;

            unsigned int v = 0;
            if (s > 0) {
                const int tp = dir ? (t + 1) : (t - 1);
                const unsigned int* hp =
                    (const unsigned int*)(hout + (size_t)tp * HH) + tid;
                do {
                    v = __hip_atomic_load(hp, __ATOMIC_RELAXED,
                                          __HIP_MEMORY_SCOPE_AGENT);
                } while (v == SENT);
            }
            sm.wk.h_lds[p][tid] = __uint_as_float(v);
            __syncthreads();                               // barrier 1

            float hv[8];
#pragma unroll
            for (int k = 0; k < 8; k++) hv[k] = sm.wk.h_lds[p][k * 64 + lane];

            float acc[16];
#pragma unroll
            for (int rr = 0; rr < 16; rr++) {
                float a = 0.f;
#pragma unroll
                for (int k = 0; k < 8; k++) a += w[rr][k] * hv[k];
                acc[rr] = a;
            }

            {
                const bool b0 = lane & 1;
#pragma unroll
                for (int r = 0; r < 8; r++) {
                    const float send = b0 ? acc[r] : acc[r + 8];
                    const float recv = __shfl_xor(send, 1, 64);
                    acc[r] = (b0 ? acc[r + 8] : acc[r]) + recv;
                }
                const bool b1 = lane & 2;
#pragma unroll
                for (int r = 0; r < 4; r++) {
                    const float send = b1 ? acc[r] : acc[r + 4];
                    const float recv = __shfl_xor(send, 2, 64);
                    acc[r] = (b1 ? acc[r + 4] : acc[r]) + recv;
                }
                const bool b2 = lane & 4;
#pragma unroll
                for (int r = 0; r < 2; r++) {
                    const float send = b2 ? acc[r] : acc[r + 2];
                    const float recv = __shfl_xor(send, 4, 64);
                    acc[r] = (b2 ? acc[r + 2] : acc[r]) + recv;
                }
                const bool b3 = lane & 8;
                {
                    const float send = b3 ? acc[0] : acc[1];
                    const float recv = __shfl_xor(send, 8, 64);
                    acc[0] = (b3 ? acc[1] : acc[0]) + recv;
                }
                acc[0] += __shfl_xor(acc[0], 16, 64);
                acc[0] += __shfl_xor(acc[0], 32, 64);
            }
            if (lane < 16) {
                const int R = ((lane & 1) << 3) | ((lane & 2) << 1) |
                              ((lane & 4) >> 1) | ((lane & 8) >> 3);
                sm.wk.glds[wave][R] = acc[0];
            }
            __syncthreads();                               // barrier 2

            if (tid < 32) {
                const int jh_ = tid >> 4;
                const int rr  = tid & 15;
                float iv = sm.wk.glds[0 + jh_][rr] + xq0;
                float fv = sm.wk.glds[2 + jh_][rr] + xq1;
                float gv = sm.wk.glds[4 + jh_][rr] + xq2;
                float ov = sm.wk.glds[6 + jh_][rr] + xq3;
                iv = 1.f / (1.f + expf(-iv));
                fv = 1.f / (1.f + expf(-fv));
                gv = tanhf(gv);
                ov = 1.f / (1.f + expf(-ov));
                c_state = fv * c_state + iv * gv;
                const float hval = ov * tanhf(c_state);
                __hip_atomic_store((unsigned int*)&hout[(size_t)t * HH + uu],
                                   __float_as_uint(hval), __ATOMIC_RELAXED,
                                   __HIP_MEMORY_SCOPE_AGENT);
                if (s + 1 < L) {
                    const int tn = dir ? (t - 1) : (t + 1);
                    if ((tn & 63) == (dir ? 63 : 0)) wait_chunk(tn >> 6);
                    const float* xgt = xg + (size_t)tn * G4;
                    xq0 = aload_f(xgt + uu);
                    xq1 = aload_f(xgt + HH + uu);
                    xq2 = aload_f(xgt + 2 * HH + uu);
                    xq3 = aload_f(xgt + 3 * HH + uu);
                }
            }
        }
        return;
    }

    if (bid == VITB) {
        // =================== VITERBI block (1 wave) ===================
        if (tid >= 64) return;   // single wave; no __syncthreads below

        // replicated transition matrix + per-lane argmax row + terminal row
        float tr[T_TAG][T_TAG];
#pragma unroll
        for (int i = 0; i < T_TAG; i++)
#pragma unroll
            for (int j = 0; j < T_TAG; j++) tr[i][j] = trans[i * T_TAG + j];

        const int d = tid % T_TAG;
        float trd[T_TAG];
#pragma unroll
        for (int j = 0; j < T_TAG; j++) trd[j] = trans[d * T_TAG + j];
        float trS[T_TAG];
#pragma unroll
        for (int j = 0; j < T_TAG; j++) trS[j] = trans[STOP_TAG * T_TAG + j];

        float fv0 = NEGV, fv1 = NEGV, fv2 = NEGV, fv3 = NEGV,
              fv4 = 0.f,  fv5 = NEGV, fv6 = NEGV;   // START_TAG = 4

        // per-slot "needs sentinel check" mask: column 7 is padding, never
        // scanned -> never wait on it (it IS written 0 by helpers, but do
        // not depend on that for liveness)
        bool need[4];
#pragma unroll
        for (int k = 0; k < 4; k++) need[k] = (((tid * 4 + k) & 7) != 7);

        // ---- stage batch 0 (32 rows) with backoff poll ----
        {
            unsigned int v[4] = { SENT, SENT, SENT, SENT };
            int tries = 0;
            for (;;) {
                bool ok = true;
#pragma unroll
                for (int k = 0; k < 4; k++) {
                    const int idx = tid * 4 + k;
                    if (need[k] && v[k] == SENT)
                        v[k] = aload_u(feats + (size_t)(idx >> 3) * 8 + (idx & 7));
                    ok &= (!need[k]) || (v[k] != SENT);
                }
                if (ok) break;
                if (++tries > 2) __builtin_amdgcn_s_sleep(16);
            }
#pragma unroll
            for (int k = 0; k < 4; k++) {
                const int idx = tid * 4 + k;
                sm.vt.stage[0][idx >> 3][idx & 7] =
                    need[k] ? __uint_as_float(v[k]) : 0.f;
            }
        }

        unsigned int pf[4];
        // issue loads for batch 1 (in flight during scan of batch 0)
#pragma unroll
        for (int k = 0; k < 4; k++) {
            const int idx = tid * 4 + k;
            pf[k] = aload_u(feats + (size_t)(32 + (idx >> 3)) * 8 + (idx & 7));
        }

#define VMAXROW(I, OUT, FI)                                                    \
        {                                                                      \
            const float a0 = fv0 + tr[I][0], a1 = fv1 + tr[I][1];              \
            const float a2 = fv2 + tr[I][2], a3 = fv3 + tr[I][3];              \
            const float a4 = fv4 + tr[I][4], a5 = fv5 + tr[I][5];              \
            const float a6 = fv6 + tr[I][6];                                   \
            const float m012 = fmaxf(fmaxf(a0, a1), a2);                       \
            const float m345 = fmaxf(fmaxf(a3, a4), a5);                       \
            OUT = fmaxf(fmaxf(m012, m345), a6) + (FI);                         \
        }

        for (int b = 0; b < 128; b++) {
            const int cur = b & 1;
            const int t0 = b * 32;
#pragma unroll 8
            for (int q = 0; q < 32; q++) {
                const int T = t0 + q;
                const float4 fa = *(const float4*)&sm.vt.stage[cur][q][0];
                const float4 fb = *(const float4*)&sm.vt.stage[cur][q][4];
                // per-lane argmax for dest d (first-index tie-break)
                {
                    float bv_ = fv0 + trd[0]; int bj_ = 0; float c_;
                    c_ = fv1 + trd[1]; if (c_ > bv_) { bv_ = c_; bj_ = 1; }
                    c_ = fv2 + trd[2]; if (c_ > bv_) { bv_ = c_; bj_ = 2; }
                    c_ = fv3 + trd[3]; if (c_ > bv_) { bv_ = c_; bj_ = 3; }
                    c_ = fv4 + trd[4]; if (c_ > bv_) { bv_ = c_; bj_ = 4; }
                    c_ = fv5 + trd[5]; if (c_ > bv_) { bv_ = c_; bj_ = 5; }
                    c_ = fv6 + trd[6]; if (c_ > bv_) { bv_ = c_; bj_ = 6; }
                    if (tid < T_TAG) sm.vt.bp[T][tid] = (unsigned char)bj_;
                }
                float nf0, nf1, nf2, nf3, nf4, nf5, nf6;
                VMAXROW(0, nf0, fa.x) VMAXROW(1, nf1, fa.y) VMAXROW(2, nf2, fa.z)
                VMAXROW(3, nf3, fa.w) VMAXROW(4, nf4, fb.x) VMAXROW(5, nf5, fb.y)
                VMAXROW(6, nf6, fb.z)
                fv0 = nf0; fv1 = nf1; fv2 = nf2; fv3 = nf3;
                fv4 = nf4; fv5 = nf5; fv6 = nf6;
            }
            if (b + 1 < 128) {
                // resolve batch b+1 (cols 0..6 only), stage it
#pragma unroll
                for (int k = 0; k < 4; k++) {
                    const int idx = tid * 4 + k;
                    if (need[k]) {
                        while (pf[k] == SENT)
                            pf[k] = aload_u(feats +
                                    (size_t)((b + 1) * 32 + (idx >> 3)) * 8 + (idx & 7));
                        sm.vt.stage[cur ^ 1][idx >> 3][idx & 7] = __uint_as_float(pf[k]);
                    } else {
                        sm.vt.stage[cur ^ 1][idx >> 3][idx & 7] = 0.f;
                    }
                }
                if (b + 2 < 128) {
#pragma unroll
                    for (int k = 0; k < 4; k++) {
                        const int idx = tid * 4 + k;
                        pf[k] = aload_u(feats +
                                (size_t)((b + 2) * 32 + (idx >> 3)) * 8 + (idx & 7));
                    }
                }
            }
        }
#undef VMAXROW

        // terminal argmax
        int bt_final; float best_score;
        {
            float bv_ = fv0 + trS[0]; int bj_ = 0; float c_;
            c_ = fv1 + trS[1]; if (c_ > bv_) { bv_ = c_; bj_ = 1; }
            c_ = fv2 + trS[2]; if (c_ > bv_) { bv_ = c_; bj_ = 2; }
            c_ = fv3 + trS[3]; if (c_ > bv_) { bv_ = c_; bj_ = 3; }
            c_ = fv4 + trS[4]; if (c_ > bv_) { bv_ = c_; bj_ = 4; }
            c_ = fv5 + trS[5]; if (c_ > bv_) { bv_ = c_; bj_ = 5; }
            c_ = fv6 + trS[6]; if (c_ > bv_) { bv_ = c_; bj_ = 6; }
            bt_final = bj_; best_score = bv_;
        }

        // ---- parallel backtrace (single wave: lockstep, no barriers) ----
        const int lo = 64 * tid + 1;
        const int hi = (tid == 63) ? (L - 1) : (64 * tid + 64);
        {
            unsigned int c0 = 0, c1 = 1, c2 = 2, c3 = 3, c4 = 4, c5 = 5, c6 = 6;
            for (int t = hi; t >= lo; --t) {
                const unsigned char* row = &sm.vt.bp[t][0];
                c0 = row[c0]; c1 = row[c1]; c2 = row[c2]; c3 = row[c3];
                c4 = row[c4]; c5 = row[c5]; c6 = row[c6];
            }
            sm.vt.gl[tid][0] = (unsigned char)c0; sm.vt.gl[tid][1] = (unsigned char)c1;
            sm.vt.gl[tid][2] = (unsigned char)c2; sm.vt.gl[tid][3] = (unsigned char)c3;
            sm.vt.gl[tid][4] = (unsigned char)c4; sm.vt.gl[tid][5] = (unsigned char)c5;
            sm.vt.gl[tid][6] = (unsigned char)c6;
        }
        if (tid == 0) {
            int b = bt_final;
            for (int l2 = 63; l2 >= 0; --l2) {
                sm.vt.bnd[l2] = (unsigned char)b;
                b = sm.vt.gl[l2][b];
            }
        }
        {
            int tag = sm.vt.bnd[tid];
            for (int t = hi; t >= lo; --t) {
                tag = sm.vt.bp[t][tag];
                out[t - 1] = (float)tag;
            }
        }
        if (tid == 63) {
            out[L - 1] = (float)bt_final;
            out[L]     = best_score;
        }
        return;
    }

    // ====================== HELPER blocks ======================
    const int hid_ = bid - (NWRK + 1);         // 0..222

    for (int tile = hid_; tile < NTILE; tile += NHELP) {
        const int jt = tile & 31;
        const int sd = tile >> 5;
        const int dr = sd & 1;
        const int sc = sd >> 1;
        const int t0 = dr ? (L - 64 - sc * 64) : (sc * 64);
        const int j0 = jt * 64;
        const float* __restrict__ wih = dr ? wih_b : wih_f;
        const float* __restrict__ bih = dr ? bih_b : bih_f;
        const float* __restrict__ bhh = dr ? bhh_b : bhh_f;
        float* __restrict__ xg = dr ? xg_b : xg_f;

        if (tid < 64) sm.hp.sent[tid] = sentence[t0 + tid];

        const int li = tid >> 3;
        const int k4 = (tid & 7) * 4;
        const int tx = tid & 15;
        const int ty = tid >> 4;

        float a00 = 0.f, a01 = 0.f, a02 = 0.f, a03 = 0.f;
        float a10 = 0.f, a11 = 0.f, a12 = 0.f, a13 = 0.f;

        for (int k0 = 0; k0 < E; k0 += 32) {
            __syncthreads();
            {
                const float4 av = *(const float4*)(emb + (size_t)sm.hp.sent[li] * E + k0 + k4);
                sm.hp.As[k4 + 0][li] = av.x; sm.hp.As[k4 + 1][li] = av.y;
                sm.hp.As[k4 + 2][li] = av.z; sm.hp.As[k4 + 3][li] = av.w;
                const float4 bv = *(const float4*)(wih + (size_t)(j0 + li) * E + k0 + k4);
                sm.hp.Bs[k4 + 0][li] = bv.x; sm.hp.Bs[k4 + 1][li] = bv.y;
                sm.hp.Bs[k4 + 2][li] = bv.z; sm.hp.Bs[k4 + 3][li] = bv.w;
            }
            __syncthreads();
#pragma unroll
            for (int k = 0; k < 32; k++) {
                const float a0 = sm.hp.As[k][ty * 2 + 0];
                const float a1 = sm.hp.As[k][ty * 2 + 1];
                const float4 b4 = *(const float4*)&sm.hp.Bs[k][tx * 4];
                a00 += a0 * b4.x; a01 += a0 * b4.y; a02 += a0 * b4.z; a03 += a0 * b4.w;
                a10 += a1 * b4.x; a11 += a1 * b4.y; a12 += a1 * b4.z; a13 += a1 * b4.w;
            }
        }

        {
            const int c0 = j0 + tx * 4;
            const float bsum0 = bih[c0 + 0] + bhh[c0 + 0];
            const float bsum1 = bih[c0 + 1] + bhh[c0 + 1];
            const float bsum2 = bih[c0 + 2] + bhh[c0 + 2];
            const float bsum3 = bih[c0 + 3] + bhh[c0 + 3];
            float* r0 = xg + (size_t)(t0 + ty * 2 + 0) * G4 + c0;
            float* r1 = xg + (size_t)(t0 + ty * 2 + 1) * G4 + c0;
            astore_f(r0 + 0, a00 + bsum0); astore_f(r0 + 1, a01 + bsum1);
            astore_f(r0 + 2, a02 + bsum2); astore_f(r0 + 3, a03 + bsum3);
            astore_f(r1 + 0, a10 + bsum0); astore_f(r1 + 1, a11 + bsum1);
            astore_f(r1 + 2, a12 + bsum2); astore_f(r1 + 3, a13 + bsum3);
        }
        __syncthreads();
        if (tid == 0)
            __hip_atomic_fetch_add(&cnt[dr * 64 + (t0 >> 6)], 1,
                                   __ATOMIC_RELEASE, __HIP_MEMORY_SCOPE_AGENT);
    }

    const int wave = tid >> 6, lane = tid & 63;
    for (int t = hid_; t < L; t += NHELP) {
        if (tid < 32) {
            const float* src = (tid < 16) ? hf : hb;
            const unsigned int* wp =
                (const unsigned int*)(src + (size_t)t * HH) + (tid & 15) * 32;
            while (__hip_atomic_load(wp, __ATOMIC_RELAXED,
                                     __HIP_MEMORY_SCOPE_AGENT) == SENT) {
                __builtin_amdgcn_s_sleep(8);
            }
        }
        __syncthreads();

        const unsigned int* p0 = (const unsigned int*)(hf + (size_t)t * HH) + tid;
        const unsigned int* p1 = (const unsigned int*)(hb + (size_t)t * HH) + tid;
        unsigned int v0, v1;
        do { v0 = __hip_atomic_load(p0, __ATOMIC_RELAXED,
                                    __HIP_MEMORY_SCOPE_AGENT); } while (v0 == SENT);
        do { v1 = __hip_atomic_load(p1, __ATOMIC_RELAXED,
                                    __HIP_MEMORY_SCOPE_AGENT); } while (v1 == SENT);
        const float x0 = __uint_as_float(v0);
        const float x1 = __uint_as_float(v1);

        float acc[T_TAG];
#pragma unroll
        for (int i = 0; i < T_TAG; i++)
            acc[i] = x0 * wout[i * HID + tid] + x1 * wout[i * HID + HH + tid];
#pragma unroll
        for (int m = 1; m < 64; m <<= 1) {
#pragma unroll
            for (int i = 0; i < T_TAG; i++) acc[i] += __shfl_xor(acc[i], m, 64);
        }
        if (lane == 0) {
#pragma unroll
            for (int i = 0; i < T_TAG; i++) sm.hp.red[wave][i] = acc[i];
        }
        __syncthreads();
        if (tid < 8) {
            // write ALL 8 columns: cols 0..6 = real feats, col 7 = 0 padding
            float ssum = 0.f;
            if (tid < T_TAG) {
                ssum = bout[tid];
#pragma unroll
                for (int wv = 0; wv < 8; wv++) ssum += sm.hp.red[wv][tid];
            }
            astore_f(&feats[(size_t)t * 8 + tid], ssum);   // visible to viterbi blk
        }
        __syncthreads();
    }
}

// ---------------------------------------------------------------------------
extern "C" void kernel_launch(void* const* d_in, const int* in_sizes, int n_in,
                              void* d_out, int out_size, void* d_ws, size_t ws_size,
                              hipStream_t stream)
{
    const int*   sentence = (const int*)  d_in[0];
    const float* emb      = (const float*)d_in[1];
    const float* wih_f    = (const float*)d_in[2];
    const float* whh_f    = (const float*)d_in[3];
    const float* bih_f    = (const float*)d_in[4];
    const float* bhh_f    = (const float*)d_in[5];
    const float* wih_b    = (const float*)d_in[6];
    const float* whh_b    = (const float*)d_in[7];
    const float* bih_b    = (const float*)d_in[8];
    const float* bhh_b    = (const float*)d_in[9];
    const float* wout     = (const float*)d_in[10];
    const float* bout     = (const float*)d_in[11];
    const float* trans    = (const float*)d_in[12];
    float* out = (float*)d_out;

    char* ws = (char*)d_ws;
    int*   cnt    = (int*)ws;                                   // 1 KiB
    float* xg_f   = (float*)(ws + 1024);
    float* xg_b   = xg_f  + (size_t)L * G4;
    float* hfbuf  = xg_b  + (size_t)L * G4;
    float* hbbuf  = hfbuf + (size_t)L * HH;
    float* featsb = hbbuf + (size_t)L * HH;
    // total: 1024 + 2*L*G4*4 + 2*L*HH*4 + L*8*4  ~= 84 MB

    // readiness counters -> 0; h buffers AND feats -> sentinel (0xFF = -NaN)
    hipMemsetAsync(cnt, 0, 1024, stream);
    hipMemsetAsync(hfbuf, 0xFF,
                   ((size_t)2 * L * HH + (size_t)L * 8) * sizeof(float), stream);

    void* args[] = { (void*)&sentence, (void*)&emb,
                     (void*)&wih_f, (void*)&bih_f, (void*)&bhh_f,
                     (void*)&wih_b, (void*)&bih_b, (void*)&bhh_b,
                     (void*)&whh_f, (void*)&whh_b,
                     (void*)&wout, (void*)&bout, (void*)&trans,
                     (void*)&xg_f, (void*)&xg_b,
                     (void*)&hfbuf, (void*)&hbbuf,
                     (void*)&featsb, (void*)&out, (void*)&cnt };
    hipLaunchCooperativeKernel((void*)fused_kernel, dim3(256),
                               dim3(512), args, 0, stream);
}

// Round 15
// 8011.936 us; speedup vs baseline: 1.1361x; 1.0889x over previous
//
#include <hip/hip_runtime.h>
#include <hip/hip_bf16.h>

// Problem constants (fixed by the reference)
#define L     4096
#define E     512
#define HID   1024
#define HH    512          // H per direction
#define G4    2048         // 4*H gate rows
#define T_TAG 7
#define START_TAG 4
#define STOP_TAG  5
#define NEGV  (-10000.0f)

#define NWRK  32           // worker blocks (16 per direction)
#define VITB  32           // viterbi block id
#define NHELP 223          // helper blocks (33..255)
#define NTILE (64 * 2 * 32)  // (L/64 s-chunks) x 2 dirs x (G4/64 j-tiles)
#define SENT  0xFFFFFFFFu  // sentinel: -NaN, unreachable for real values

__device__ __forceinline__ unsigned int aload_u(const float* p) {
    return __hip_atomic_load((const unsigned int*)p, __ATOMIC_RELAXED,
                             __HIP_MEMORY_SCOPE_AGENT);
}
__device__ __forceinline__ float aload_f(const float* p) {
    return __uint_as_float(aload_u(p));
}
__device__ __forceinline__ void astore_f(float* p, float x) {
    __hip_atomic_store((unsigned int*)p, __float_as_uint(x),
                       __ATOMIC_RELAXED, __HIP_MEMORY_SCOPE_AGENT);
}

// LDS role overlay
union SMem {
    struct { float h_lds[2][HH]; float glds[8][16]; } wk;                 // 4.6 KB
    struct { float As[32][68]; float Bs[32][68]; int sent[64];
             float red[8][8]; } hp;                                       // 17.9 KB
    struct { unsigned char bp[L][8];          // 32768: backpointers
             float gm[64][T_TAG][T_TAG];      // 12544: per-lane block matrices
             float ebuf[64][T_TAG];           //  1792: block-entry fv vectors
             float fin_score; int fin_tag;
             unsigned char gl[64][8]; unsigned char bnd[64]; } vt;        // ~47.7 KB
};

// ---------------------------------------------------------------------------
// Fused cooperative kernel, 256 blocks x 512.  (R13 structure; static roles)
//  blocks 0..31  : bidirectional LSTM recurrence (proven floor ~1.9us/step)
//  block  32     : Viterbi, (max,+) PARALLEL SCAN (1 wave):
//                  A) lane l composes 7x7 block matrix over rows [64l,64l+64)
//                  B) lane 0 walks block matrices -> block-entry fv vectors
//                  C) lane l re-scans its 64 steps exactly (bp, first-index)
//                  D) parallel backtrace (R13 verbatim)
//  blocks 33..255: helpers (xg tiles, then feats rows; agent-scope stores,
//                  all 8 cols written - col 7 = 0)
// ---------------------------------------------------------------------------
__global__ __launch_bounds__(512)
void fused_kernel(const int* __restrict__ sentence, const float* __restrict__ emb,
                  const float* __restrict__ wih_f, const float* __restrict__ bih_f,
                  const float* __restrict__ bhh_f,
                  const float* __restrict__ wih_b, const float* __restrict__ bih_b,
                  const float* __restrict__ bhh_b,
                  const float* __restrict__ whh_f, const float* __restrict__ whh_b,
                  const float* __restrict__ wout, const float* __restrict__ bout,
                  const float* __restrict__ trans,
                  float* __restrict__ xg_f, float* __restrict__ xg_b,
                  float* __restrict__ hf, float* __restrict__ hb,
                  float* __restrict__ feats, float* __restrict__ out, int* cnt)
{
    const int bid = blockIdx.x;
    const int tid = threadIdx.x;

    __shared__ SMem sm;

    if (bid < NWRK) {
        // =================== WORKER: LSTM recurrence (R13 verbatim) ==========
        const int dir = bid >> 4;
        const int rnk = bid & 15;

        const float* __restrict__ xg  = dir ? xg_b  : xg_f;
        const float* __restrict__ whh = dir ? whh_b : whh_f;
        float* __restrict__ hout = dir ? hb : hf;

        const int wave = tid >> 6;
        const int lane = tid & 63;
        const int g    = wave >> 1;
        const int jh   = wave & 1;
        const int u0   = rnk * 32;

        float w[16][8];
#pragma unroll
        for (int rr = 0; rr < 16; rr++) {
            const size_t row = (size_t)(g * HH + u0 + jh * 16 + rr);
#pragma unroll
            for (int k = 0; k < 8; k++)
                w[rr][k] = whh[row * HH + (size_t)(k * 64 + lane)];
        }

        float c_state = 0.f;
        const int uu = u0 + (tid & 31);

        auto wait_chunk = [&](int tc) {
            const int* cp = cnt + dir * 64 + tc;
            while (__hip_atomic_load(cp, __ATOMIC_ACQUIRE,
                                     __HIP_MEMORY_SCOPE_AGENT) < 32) {
                __builtin_amdgcn_s_sleep(1);
            }
        };

        float xq0 = 0.f, xq1 = 0.f, xq2 = 0.f, xq3 = 0.f;
        if (tid < 32) {
            wait_chunk(dir ? 63 : 0);
            const float* xgt = xg + (size_t)(dir ? (L - 1) : 0) * G4;
            xq0 = aload_f(xgt + uu);            xq1 = aload_f(xgt + HH + uu);
            xq2 = aload_f(xgt + 2 * HH + uu);   xq3 = aload_f(xgt + 3 * HH + uu);
        }

        for (int s = 0; s < L; s++) {
            const int t = dir ? (L - 1 - s) : s;
            const int p = s & 1;

            unsigned int v = 0;
            if (s > 0) {
                const int tp = dir ? (t + 1) : (t - 1);
                const unsigned int* hp =
                    (const unsigned int*)(hout + (size_t)tp * HH) + tid;
                do {
                    v = __hip_atomic_load(hp, __ATOMIC_RELAXED,
                                          __HIP_MEMORY_SCOPE_AGENT);
                } while (v == SENT);
            }
            sm.wk.h_lds[p][tid] = __uint_as_float(v);
            __syncthreads();                               // barrier 1

            float hv[8];
#pragma unroll
            for (int k = 0; k < 8; k++) hv[k] = sm.wk.h_lds[p][k * 64 + lane];

            float acc[16];
#pragma unroll
            for (int rr = 0; rr < 16; rr++) {
                float a = 0.f;
#pragma unroll
                for (int k = 0; k < 8; k++) a += w[rr][k] * hv[k];
                acc[rr] = a;
            }

            {
                const bool b0 = lane & 1;
#pragma unroll
                for (int r = 0; r < 8; r++) {
                    const float send = b0 ? acc[r] : acc[r + 8];
                    const float recv = __shfl_xor(send, 1, 64);
                    acc[r] = (b0 ? acc[r + 8] : acc[r]) + recv;
                }
                const bool b1 = lane & 2;
#pragma unroll
                for (int r = 0; r < 4; r++) {
                    const float send = b1 ? acc[r] : acc[r + 4];
                    const float recv = __shfl_xor(send, 2, 64);
                    acc[r] = (b1 ? acc[r + 4] : acc[r]) + recv;
                }
                const bool b2 = lane & 4;
#pragma unroll
                for (int r = 0; r < 2; r++) {
                    const float send = b2 ? acc[r] : acc[r + 2];
                    const float recv = __shfl_xor(send, 4, 64);
                    acc[r] = (b2 ? acc[r + 2] : acc[r]) + recv;
                }
                const bool b3 = lane & 8;
                {
                    const float send = b3 ? acc[0] : acc[1];
                    const float recv = __shfl_xor(send, 8, 64);
                    acc[0] = (b3 ? acc[1] : acc[0]) + recv;
                }
                acc[0] += __shfl_xor(acc[0], 16, 64);
                acc[0] += __shfl_xor(acc[0], 32, 64);
            }
            if (lane < 16) {
                const int R = ((lane & 1) << 3) | ((lane & 2) << 1) |
                              ((lane & 4) >> 1) | ((lane & 8) >> 3);
                sm.wk.glds[wave][R] = acc[0];
            }
            __syncthreads();                               // barrier 2

            if (tid < 32) {
                const int jh_ = tid >> 4;
                const int rr  = tid & 15;
                float iv = sm.wk.glds[0 + jh_][rr] + xq0;
                float fv = sm.wk.glds[2 + jh_][rr] + xq1;
                float gv = sm.wk.glds[4 + jh_][rr] + xq2;
                float ov = sm.wk.glds[6 + jh_][rr] + xq3;
                iv = 1.f / (1.f + expf(-iv));
                fv = 1.f / (1.f + expf(-fv));
                gv = tanhf(gv);
                ov = 1.f / (1.f + expf(-ov));
                c_state = fv * c_state + iv * gv;
                const float hval = ov * tanhf(c_state);
                __hip_atomic_store((unsigned int*)&hout[(size_t)t * HH + uu],
                                   __float_as_uint(hval), __ATOMIC_RELAXED,
                                   __HIP_MEMORY_SCOPE_AGENT);
                if (s + 1 < L) {
                    const int tn = dir ? (t - 1) : (t + 1);
                    if ((tn & 63) == (dir ? 63 : 0)) wait_chunk(tn >> 6);
                    const float* xgt = xg + (size_t)tn * G4;
                    xq0 = aload_f(xgt + uu);
                    xq1 = aload_f(xgt + HH + uu);
                    xq2 = aload_f(xgt + 2 * HH + uu);
                    xq3 = aload_f(xgt + 3 * HH + uu);
                }
            }
        }
        return;
    }

    if (bid == VITB) {
        // ======== VITERBI block (1 wave): (max,+) parallel scan ========
        if (tid >= 64) return;   // single wave; no __syncthreads below

        // replicated transition matrix + terminal row (registers, static idx)
        float tr[T_TAG][T_TAG];
#pragma unroll
        for (int i = 0; i < T_TAG; i++)
#pragma unroll
            for (int j = 0; j < T_TAG; j++) tr[i][j] = trans[i * T_TAG + j];
        float trS[T_TAG];
#pragma unroll
        for (int j = 0; j < T_TAG; j++) trS[j] = trans[STOP_TAG * T_TAG + j];

        const int t0 = tid * 64;    // my block of 64 timesteps

        // ---- Phase A: compose M = A_{t0+63} (x) ... (x) A_{t0} ----
        // A_t[i][j] = tr[i][j] + feat_t[i].  In-place column update keeps
        // register count low (M 49 + col 7 + f 7).
        float M[T_TAG][T_TAG];
        float f[T_TAG];
        {
            // poll + load row t0 (cols 0..6; col 7 is padding, never polled)
#pragma unroll
            for (int i = 0; i < T_TAG; i++) {
                unsigned int v;
                const float* p = feats + (size_t)t0 * 8 + i;
                do { v = aload_u(p); } while (v == SENT);
                f[i] = __uint_as_float(v);
            }
#pragma unroll
            for (int i = 0; i < T_TAG; i++)
#pragma unroll
                for (int j = 0; j < T_TAG; j++) M[i][j] = tr[i][j] + f[i];
        }
        for (int q = 1; q < 64; q++) {
            const int T = t0 + q;
#pragma unroll
            for (int i = 0; i < T_TAG; i++) {
                unsigned int v;
                const float* p = feats + (size_t)T * 8 + i;
                do { v = aload_u(p); } while (v == SENT);
                f[i] = __uint_as_float(v);
            }
            // M' = A_T (x) M :  M'[i][j] = f[i] + max_k(tr[i][k] + M[k][j])
#pragma unroll
            for (int j = 0; j < T_TAG; j++) {
                float c[T_TAG];
#pragma unroll
                for (int k = 0; k < T_TAG; k++) c[k] = M[k][j];
#pragma unroll
                for (int i = 0; i < T_TAG; i++) {
                    float m = tr[i][0] + c[0];
#pragma unroll
                    for (int k = 1; k < T_TAG; k++)
                        m = fmaxf(m, tr[i][k] + c[k]);
                    M[i][j] = f[i] + m;
                }
            }
        }

        // ---- Phase B: block-entry vectors via lane-0 serial walk ----
#pragma unroll
        for (int i = 0; i < T_TAG; i++)
#pragma unroll
            for (int j = 0; j < T_TAG; j++) sm.vt.gm[tid][i][j] = M[i][j];
        asm volatile("s_waitcnt lgkmcnt(0)" ::: "memory");

        if (tid == 0) {
            float e[T_TAG];
#pragma unroll
            for (int i = 0; i < T_TAG; i++)
                e[i] = (i == START_TAG) ? 0.f : NEGV;
#pragma unroll
            for (int i = 0; i < T_TAG; i++) sm.vt.ebuf[0][i] = e[i];
            for (int l = 0; l < 63; l++) {
                float en[T_TAG];
#pragma unroll
                for (int i = 0; i < T_TAG; i++) {
                    float m = sm.vt.gm[l][i][0] + e[0];
#pragma unroll
                    for (int k = 1; k < T_TAG; k++)
                        m = fmaxf(m, sm.vt.gm[l][i][k] + e[k]);
                    en[i] = m;
                }
#pragma unroll
                for (int i = 0; i < T_TAG; i++) {
                    e[i] = en[i];
                    sm.vt.ebuf[l + 1][i] = e[i];
                }
            }
        }
        asm volatile("s_waitcnt lgkmcnt(0)" ::: "memory");

        // ---- Phase C: exact per-block re-scan (bp + final fv) ----
        float fv0 = sm.vt.ebuf[tid][0], fv1 = sm.vt.ebuf[tid][1],
              fv2 = sm.vt.ebuf[tid][2], fv3 = sm.vt.ebuf[tid][3],
              fv4 = sm.vt.ebuf[tid][4], fv5 = sm.vt.ebuf[tid][5],
              fv6 = sm.vt.ebuf[tid][6];

#define ADEST(I, T, NF)                                                        \
        {                                                                      \
            float bv_ = fv0 + tr[I][0]; int bj_ = 0; float c_;                 \
            c_ = fv1 + tr[I][1]; if (c_ > bv_) { bv_ = c_; bj_ = 1; }          \
            c_ = fv2 + tr[I][2]; if (c_ > bv_) { bv_ = c_; bj_ = 2; }          \
            c_ = fv3 + tr[I][3]; if (c_ > bv_) { bv_ = c_; bj_ = 3; }          \
            c_ = fv4 + tr[I][4]; if (c_ > bv_) { bv_ = c_; bj_ = 4; }          \
            c_ = fv5 + tr[I][5]; if (c_ > bv_) { bv_ = c_; bj_ = 5; }          \
            c_ = fv6 + tr[I][6]; if (c_ > bv_) { bv_ = c_; bj_ = 6; }          \
            sm.vt.bp[(T)][I] = (unsigned char)bj_;                             \
            NF = bv_ + f[I];                                                   \
        }

        for (int q = 0; q < 64; q++) {
            const int T = t0 + q;
#pragma unroll
            for (int i = 0; i < T_TAG; i++)
                f[i] = aload_f(feats + (size_t)T * 8 + i);   // already published
            float nf0, nf1, nf2, nf3, nf4, nf5, nf6;
            ADEST(0, T, nf0) ADEST(1, T, nf1) ADEST(2, T, nf2)
            ADEST(3, T, nf3) ADEST(4, T, nf4) ADEST(5, T, nf5)
            ADEST(6, T, nf6)
            fv0 = nf0; fv1 = nf1; fv2 = nf2; fv3 = nf3;
            fv4 = nf4; fv5 = nf5; fv6 = nf6;
        }
#undef ADEST

        // terminal argmax on lane 63 (holds fv after t = L-1)
        if (tid == 63) {
            float bv_ = fv0 + trS[0]; int bj_ = 0; float c_;
            c_ = fv1 + trS[1]; if (c_ > bv_) { bv_ = c_; bj_ = 1; }
            c_ = fv2 + trS[2]; if (c_ > bv_) { bv_ = c_; bj_ = 2; }
            c_ = fv3 + trS[3]; if (c_ > bv_) { bv_ = c_; bj_ = 3; }
            c_ = fv4 + trS[4]; if (c_ > bv_) { bv_ = c_; bj_ = 4; }
            c_ = fv5 + trS[5]; if (c_ > bv_) { bv_ = c_; bj_ = 5; }
            c_ = fv6 + trS[6]; if (c_ > bv_) { bv_ = c_; bj_ = 6; }
            sm.vt.fin_tag = bj_;
            sm.vt.fin_score = bv_;
        }
        asm volatile("s_waitcnt lgkmcnt(0)" ::: "memory");
        const int bt_final = sm.vt.fin_tag;
        const float best_score = sm.vt.fin_score;

        // ---- Phase D: parallel backtrace (R13 verbatim) ----
        const int lo = 64 * tid + 1;
        const int hi = (tid == 63) ? (L - 1) : (64 * tid + 64);
        {
            unsigned int c0 = 0, c1 = 1, c2 = 2, c3 = 3, c4 = 4, c5 = 5, c6 = 6;
            for (int t = hi; t >= lo; --t) {
                const unsigned char* row = &sm.vt.bp[t][0];
                c0 = row[c0]; c1 = row[c1]; c2 = row[c2]; c3 = row[c3];
                c4 = row[c4]; c5 = row[c5]; c6 = row[c6];
            }
            sm.vt.gl[tid][0] = (unsigned char)c0; sm.vt.gl[tid][1] = (unsigned char)c1;
            sm.vt.gl[tid][2] = (unsigned char)c2; sm.vt.gl[tid][3] = (unsigned char)c3;
            sm.vt.gl[tid][4] = (unsigned char)c4; sm.vt.gl[tid][5] = (unsigned char)c5;
            sm.vt.gl[tid][6] = (unsigned char)c6;
        }
        asm volatile("s_waitcnt lgkmcnt(0)" ::: "memory");
        if (tid == 0) {
            int b = bt_final;
            for (int l2 = 63; l2 >= 0; --l2) {
                sm.vt.bnd[l2] = (unsigned char)b;
                b = sm.vt.gl[l2][b];
            }
        }
        asm volatile("s_waitcnt lgkmcnt(0)" ::: "memory");
        {
            int tag = sm.vt.bnd[tid];
            for (int t = hi; t >= lo; --t) {
                tag = sm.vt.bp[t][tag];
                out[t - 1] = (float)tag;
            }
        }
        if (tid == 63) {
            out[L - 1] = (float)bt_final;
            out[L]     = best_score;
        }
        return;
    }

    // ====================== HELPER blocks (R13 verbatim) ======================
    const int hid_ = bid - (NWRK + 1);         // 0..222

    for (int tile = hid_; tile < NTILE; tile += NHELP) {
        const int jt = tile & 31;
        const int sd = tile >> 5;
        const int dr = sd & 1;
        const int sc = sd >> 1;
        const int t0 = dr ? (L - 64 - sc * 64) : (sc * 64);
        const int j0 = jt * 64;
        const float* __restrict__ wih = dr ? wih_b : wih_f;
        const float* __restrict__ bih = dr ? bih_b : bih_f;
        const float* __restrict__ bhh = dr ? bhh_b : bhh_f;
        float* __restrict__ xg = dr ? xg_b : xg_f;

        if (tid < 64) sm.hp.sent[tid] = sentence[t0 + tid];

        const int li = tid >> 3;
        const int k4 = (tid & 7) * 4;
        const int tx = tid & 15;
        const int ty = tid >> 4;

        float a00 = 0.f, a01 = 0.f, a02 = 0.f, a03 = 0.f;
        float a10 = 0.f, a11 = 0.f, a12 = 0.f, a13 = 0.f;

        for (int k0 = 0; k0 < E; k0 += 32) {
            __syncthreads();
            {
                const float4 av = *(const float4*)(emb + (size_t)sm.hp.sent[li] * E + k0 + k4);
                sm.hp.As[k4 + 0][li] = av.x; sm.hp.As[k4 + 1][li] = av.y;
                sm.hp.As[k4 + 2][li] = av.z; sm.hp.As[k4 + 3][li] = av.w;
                const float4 bv = *(const float4*)(wih + (size_t)(j0 + li) * E + k0 + k4);
                sm.hp.Bs[k4 + 0][li] = bv.x; sm.hp.Bs[k4 + 1][li] = bv.y;
                sm.hp.Bs[k4 + 2][li] = bv.z; sm.hp.Bs[k4 + 3][li] = bv.w;
            }
            __syncthreads();
#pragma unroll
            for (int k = 0; k < 32; k++) {
                const float a0 = sm.hp.As[k][ty * 2 + 0];
                const float a1 = sm.hp.As[k][ty * 2 + 1];
                const float4 b4 = *(const float4*)&sm.hp.Bs[k][tx * 4];
                a00 += a0 * b4.x; a01 += a0 * b4.y; a02 += a0 * b4.z; a03 += a0 * b4.w;
                a10 += a1 * b4.x; a11 += a1 * b4.y; a12 += a1 * b4.z; a13 += a1 * b4.w;
            }
        }

        {
            const int c0 = j0 + tx * 4;
            const float bsum0 = bih[c0 + 0] + bhh[c0 + 0];
            const float bsum1 = bih[c0 + 1] + bhh[c0 + 1];
            const float bsum2 = bih[c0 + 2] + bhh[c0 + 2];
            const float bsum3 = bih[c0 + 3] + bhh[c0 + 3];
            float* r0 = xg + (size_t)(t0 + ty * 2 + 0) * G4 + c0;
            float* r1 = xg + (size_t)(t0 + ty * 2 + 1) * G4 + c0;
            astore_f(r0 + 0, a00 + bsum0); astore_f(r0 + 1, a01 + bsum1);
            astore_f(r0 + 2, a02 + bsum2); astore_f(r0 + 3, a03 + bsum3);
            astore_f(r1 + 0, a10 + bsum0); astore_f(r1 + 1, a11 + bsum1);
            astore_f(r1 + 2, a12 + bsum2); astore_f(r1 + 3, a13 + bsum3);
        }
        __syncthreads();
        if (tid == 0)
            __hip_atomic_fetch_add(&cnt[dr * 64 + (t0 >> 6)], 1,
                                   __ATOMIC_RELEASE, __HIP_MEMORY_SCOPE_AGENT);
    }

    const int wave = tid >> 6, lane = tid & 63;
    for (int t = hid_; t < L; t += NHELP) {
        if (tid < 32) {
            const float* src = (tid < 16) ? hf : hb;
            const unsigned int* wp =
                (const unsigned int*)(src + (size_t)t * HH) + (tid & 15) * 32;
            while (__hip_atomic_load(wp, __ATOMIC_RELAXED,
                                     __HIP_MEMORY_SCOPE_AGENT) == SENT) {
                __builtin_amdgcn_s_sleep(8);
            }
        }
        __syncthreads();

        const unsigned int* p0 = (const unsigned int*)(hf + (size_t)t * HH) + tid;
        const unsigned int* p1 = (const unsigned int*)(hb + (size_t)t * HH) + tid;
        unsigned int v0, v1;
        do { v0 = __hip_atomic_load(p0, __ATOMIC_RELAXED,
                                    __HIP_MEMORY_SCOPE_AGENT); } while (v0 == SENT);
        do { v1 = __hip_atomic_load(p1, __ATOMIC_RELAXED,
                                    __HIP_MEMORY_SCOPE_AGENT); } while (v1 == SENT);
        const float x0 = __uint_as_float(v0);
        const float x1 = __uint_as_float(v1);

        float acc[T_TAG];
#pragma unroll
        for (int i = 0; i < T_TAG; i++)
            acc[i] = x0 * wout[i * HID + tid] + x1 * wout[i * HID + HH + tid];
#pragma unroll
        for (int m = 1; m < 64; m <<= 1) {
#pragma unroll
            for (int i = 0; i < T_TAG; i++) acc[i] += __shfl_xor(acc[i], m, 64);
        }
        if (lane == 0) {
#pragma unroll
            for (int i = 0; i < T_TAG; i++) sm.hp.red[wave][i] = acc[i];
        }
        __syncthreads();
        if (tid < 8) {
            float ssum = 0.f;
            if (tid < T_TAG) {
                ssum = bout[tid];
#pragma unroll
                for (int wv = 0; wv < 8; wv++) ssum += sm.hp.red[wv][tid];
            }
            astore_f(&feats[(size_t)t * 8 + tid], ssum);
        }
        __syncthreads();
    }
}

// ---------------------------------------------------------------------------
extern "C" void kernel_launch(void* const* d_in, const int* in_sizes, int n_in,
                              void* d_out, int out_size, void* d_ws, size_t ws_size,
                              hipStream_t stream)
{
    const int*   sentence = (const int*)  d_in[0];
    const float* emb      = (const float*)d_in[1];
    const float* wih_f    = (const float*)d_in[2];
    const float* whh_f    = (const float*)d_in[3];
    const float* bih_f    = (const float*)d_in[4];
    const float* bhh_f    = (const float*)d_in[5];
    const float* wih_b    = (const float*)d_in[6];
    const float* whh_b    = (const float*)d_in[7];
    const float* bih_b    = (const float*)d_in[8];
    const float* bhh_b    = (const float*)d_in[9];
    const float* wout     = (const float*)d_in[10];
    const float* bout     = (const float*)d_in[11];
    const float* trans    = (const float*)d_in[12];
    float* out = (float*)d_out;

    char* ws = (char*)d_ws;
    int*   cnt    = (int*)ws;                                   // 1 KiB
    float* xg_f   = (float*)(ws + 1024);
    float* xg_b   = xg_f  + (size_t)L * G4;
    float* hfbuf  = xg_b  + (size_t)L * G4;
    float* hbbuf  = hfbuf + (size_t)L * HH;
    float* featsb = hbbuf + (size_t)L * HH;
    // total: 1024 + 2*L*G4*4 + 2*L*HH*4 + L*8*4  ~= 84 MB

    // readiness counters -> 0; h buffers AND feats -> sentinel (0xFF = -NaN)
    hipMemsetAsync(cnt, 0, 1024, stream);
    hipMemsetAsync(hfbuf, 0xFF,
                   ((size_t)2 * L * HH + (size_t)L * 8) * sizeof(float), stream);

    void* args[] = { (void*)&sentence, (void*)&emb,
                     (void*)&wih_f, (void*)&bih_f, (void*)&bhh_f,
                     (void*)&wih_b, (void*)&bih_b, (void*)&bhh_b,
                     (void*)&whh_f, (void*)&whh_b,
                     (void*)&wout, (void*)&bout, (void*)&trans,
                     (void*)&xg_f, (void*)&xg_b,
                     (void*)&hfbuf, (void*)&hbbuf,
                     (void*)&featsb, (void*)&out, (void*)&cnt };
    hipLaunchCooperativeKernel((void*)fused_kernel, dim3(256),
                               dim3(512), args, 0, stream);
}